// Round 6
// baseline (4770.413 us; speedup 1.0000x reference)
//
#include <hip/hip_runtime.h>
#include <stdint.h>

// Persistent producer-consumer 2-layer LSTM, split-bf16, MI355X.
// 8 batch clusters x 2 layers x 16 hidden-slices = 256 wgs (1/CU).
// h carried as pre-split bf16 hi/lo planes in ws rings (depth 8).
// No fences, no atomics: per-slice token flags (t+1) via sc0sc1 stores,
// vector-polled; ring data via sc0sc1 loads/stores (coherence point).
// Weights in regs (bf16 hi+lo); gates = Whi*xhi + Whi*xlo + Wlo*xhi via
// mfma_f32_16x16x32_bf16, K split over 2 interleaved accumulators.

typedef float f32x4 __attribute__((ext_vector_type(4)));
typedef short s16x8 __attribute__((ext_vector_type(8)));
typedef int   i32x4 __attribute__((ext_vector_type(4)));
typedef unsigned short u16;
typedef unsigned int u32;
typedef unsigned long long u64;

#define N_T 1024
#define RING 8
#define FSLOT 16

__device__ __forceinline__ u16 f2bf(float f) {
  u32 u = __float_as_uint(f);
  u += 0x7FFFu + ((u >> 16) & 1u);
  return (u16)(u >> 16);
}
__device__ __forceinline__ float bf2f(u16 s) { return __uint_as_float(((u32)s) << 16); }
__device__ __forceinline__ void split_bf(float v, u16& hi, u16& lo) {
  hi = f2bf(v);
  lo = f2bf(v - bf2f(hi));
}
__device__ __forceinline__ float sigm(float v) { return 1.0f / (1.0f + __expf(-v)); }

__device__ __forceinline__ void st_coh_u32(void* p, u32 v) {
  asm volatile("global_store_dword %0, %1, off sc0 sc1" :: "v"(p), "v"(v) : "memory");
}
// 2 base pointers, 32B each (2 dwordx4), single waitcnt
__device__ __forceinline__ void ld_coh_p2(const void* p0, const void* p1,
                                          i32x4& a0, i32x4& a1, i32x4& b0, i32x4& b1) {
  asm volatile(
      "global_load_dwordx4 %0, %4, off sc0 sc1\n\t"
      "global_load_dwordx4 %1, %4, off offset:16 sc0 sc1\n\t"
      "global_load_dwordx4 %2, %5, off sc0 sc1\n\t"
      "global_load_dwordx4 %3, %5, off offset:16 sc0 sc1\n\t"
      "s_waitcnt vmcnt(0)"
      : "=&v"(a0), "=&v"(a1), "=&v"(b0), "=&v"(b1)
      : "v"(p0), "v"(p1) : "memory");
}
// 4 base pointers, 32B each, single waitcnt
__device__ __forceinline__ void ld_coh_p4(const void* p0, const void* p1,
                                          const void* p2, const void* p3,
                                          i32x4& a0, i32x4& a1, i32x4& b0, i32x4& b1,
                                          i32x4& c0, i32x4& c1, i32x4& d0, i32x4& d1) {
  asm volatile(
      "global_load_dwordx4 %0, %8, off sc0 sc1\n\t"
      "global_load_dwordx4 %1, %8, off offset:16 sc0 sc1\n\t"
      "global_load_dwordx4 %2, %9, off sc0 sc1\n\t"
      "global_load_dwordx4 %3, %9, off offset:16 sc0 sc1\n\t"
      "global_load_dwordx4 %4, %10, off sc0 sc1\n\t"
      "global_load_dwordx4 %5, %10, off offset:16 sc0 sc1\n\t"
      "global_load_dwordx4 %6, %11, off sc0 sc1\n\t"
      "global_load_dwordx4 %7, %11, off offset:16 sc0 sc1\n\t"
      "s_waitcnt vmcnt(0)"
      : "=&v"(a0), "=&v"(a1), "=&v"(b0), "=&v"(b1),
        "=&v"(c0), "=&v"(c1), "=&v"(d0), "=&v"(d1)
      : "v"(p0), "v"(p1), "v"(p2), "v"(p3) : "memory");
}
__device__ __forceinline__ bool all16(const i32x4& f0, const i32x4& f1,
                                      const i32x4& f2, const i32x4& f3, int t) {
  return f0[0]==t && f0[1]==t && f0[2]==t && f0[3]==t &&
         f1[0]==t && f1[1]==t && f1[2]==t && f1[3]==t &&
         f2[0]==t && f2[1]==t && f2[2]==t && f2[3]==t &&
         f3[0]==t && f3[1]==t && f3[2]==t && f3[3]==t;
}
__device__ __forceinline__ void spin16(const u32* p, int tok) {
  for (;;) {
    i32x4 f0, f1, f2, f3;
    asm volatile(
        "global_load_dwordx4 %0, %4, off sc0 sc1\n\t"
        "global_load_dwordx4 %1, %4, off offset:16 sc0 sc1\n\t"
        "global_load_dwordx4 %2, %4, off offset:32 sc0 sc1\n\t"
        "global_load_dwordx4 %3, %4, off offset:48 sc0 sc1\n\t"
        "s_waitcnt vmcnt(0)"
        : "=&v"(f0), "=&v"(f1), "=&v"(f2), "=&v"(f3) : "v"(p) : "memory");
    if (all16(f0, f1, f2, f3, tok)) return;
  }
}
__device__ __forceinline__ void spin16x2(const u32* pA, int tokA, const u32* pB, int tokB) {
  for (;;) {
    i32x4 a0, a1, a2, a3, b0, b1, b2, b3;
    asm volatile(
        "global_load_dwordx4 %0, %8, off sc0 sc1\n\t"
        "global_load_dwordx4 %1, %8, off offset:16 sc0 sc1\n\t"
        "global_load_dwordx4 %2, %8, off offset:32 sc0 sc1\n\t"
        "global_load_dwordx4 %3, %8, off offset:48 sc0 sc1\n\t"
        "global_load_dwordx4 %4, %9, off sc0 sc1\n\t"
        "global_load_dwordx4 %5, %9, off offset:16 sc0 sc1\n\t"
        "global_load_dwordx4 %6, %9, off offset:32 sc0 sc1\n\t"
        "global_load_dwordx4 %7, %9, off offset:48 sc0 sc1\n\t"
        "s_waitcnt vmcnt(0)"
        : "=&v"(a0), "=&v"(a1), "=&v"(a2), "=&v"(a3),
          "=&v"(b0), "=&v"(b1), "=&v"(b2), "=&v"(b3)
        : "v"(pA), "v"(pB) : "memory");
    if (all16(a0, a1, a2, a3, tokA) && all16(b0, b1, b2, b3, tokB)) return;
  }
}
__device__ __forceinline__ void split8(const f32x4& a, const f32x4& b, i32x4& H, i32x4& L) {
#pragma unroll
  for (int k = 0; k < 2; ++k) {
    u16 h0, l0, h1, l1, h2, l2, h3, l3;
    const f32x4& v = k ? b : a;
    split_bf(v[0], h0, l0); split_bf(v[1], h1, l1);
    split_bf(v[2], h2, l2); split_bf(v[3], h3, l3);
    H[2 * k]     = (int)((u32)h0 | ((u32)h1 << 16));
    H[2 * k + 1] = (int)((u32)h2 | ((u32)h3 << 16));
    L[2 * k]     = (int)((u32)l0 | ((u32)l1 << 16));
    L[2 * k + 1] = (int)((u32)l2 | ((u32)l3 << 16));
  }
}

// ring element offset: plane[slot][cl8][sl16][b16][u16]
__device__ __forceinline__ size_t relem(int slot, int cl, int sl, int b) {
  return ((((size_t)slot * 8 + cl) * 16 + sl) * 16 + b) * 16;
}

template <int LAYER>
__device__ __forceinline__ void run_layer(
    int cl, int sl,
    const float* __restrict__ x,
    const float* __restrict__ Wxh, const float* __restrict__ bxh,
    const float* __restrict__ Whh, const float* __restrict__ bhh,
    const float* __restrict__ Wfc, const float* __restrict__ bfc,
    float* __restrict__ out,
    u16* r0h, u16* r0l, u16* r1h, u16* r1l,
    u32* arrive0, u32* arrive1,
    char* inbH, char* inbL, float* gatesS, float* biasS)
{
  constexpr int K   = LAYER ? 512 : 384;   // L0: [x128; h0_256]  L1: [h0_256; h1_256]
  constexpr int NKB = K / 32;
  constexpr int NH  = NKB / 2;
  constexpr int RB  = K * 2;               // LDS row bytes

  const int tid  = threadIdx.x;
  const int wv   = tid >> 6;     // wave = gate (i,f,g,o)
  const int lane = tid & 63;
  const int r15  = lane & 15;
  const int kg   = lane >> 4;

  if (tid < 64) {                // combined bias, 64 gate rows of this slice
    int g = tid >> 4, u = tid & 15;
    int row = g * 256 + sl * 16 + u;
    biasS[tid] = bxh[row] + bhh[row];
  }

  // weights: wave wv = gate wv, one 16-row M-tile: rows wv*256 + sl*16 + r15
  s16x8 wAh[NKB], wAl[NKB];
  {
    const int grow = wv * 256 + sl * 16 + r15;
#pragma unroll
    for (int kb = 0; kb < NKB; ++kb) {
      const int k0 = kb * 32 + kg * 8;
      const float* src;
      if (LAYER == 0) src = (k0 < 128) ? (Wxh + grow * 128 + k0) : (Whh + grow * 256 + (k0 - 128));
      else            src = (k0 < 256) ? (Wxh + grow * 256 + k0) : (Whh + grow * 256 + (k0 - 256));
      f32x4 a = *(const f32x4*)src;
      f32x4 b = *(const f32x4*)(src + 4);
      s16x8 vh, vl;
#pragma unroll
      for (int j = 0; j < 4; ++j) {
        u16 h, l;
        split_bf(a[j], h, l); vh[j] = (short)h; vl[j] = (short)l;
        split_bf(b[j], h, l); vh[4 + j] = (short)h; vl[4 + j] = (short)l;
      }
      wAh[kb] = vh; wAl[kb] = vl;
    }
  }

  const int slR = tid >> 4, bR = tid & 15;     // staging decomposition
  const int xorB = (bR & 7) << 4;              // write-side LDS swizzle (row = bR)
  float cpr = 0.f;                             // cell state: unit sl*16+(tid&15) @ batch tid>>4

  for (int t = 0; t < N_T; ++t) {
    // L0: prefetch + pre-split x before the wait (slR=b, bR=u8 here)
    i32x4 xH, xL;
    if (LAYER == 0) {
      const float* p = x + ((size_t)(cl * 16 + slR) * N_T + t) * 128 + bR * 8;
      f32x4 a = *(const f32x4*)p;
      f32x4 b = *(const f32x4*)(p + 4);
      split8(a, b, xH, xL);
    }

    // ---- waits (tid 0 only), token = step+1
    if (tid == 0) {
      if (LAYER == 0) {
        const u32* pa = &arrive0[(((t - 1) & (FSLOT - 1)) * 8 + cl) * 16];
        const u32* pb = &arrive1[(((t - 8) & (FSLOT - 1)) * 8 + cl) * 16];
        if (t >= 8)     spin16x2(pa, t, pb, t - 7);   // dep + slot back-pressure
        else if (t > 0) spin16(pa, t);
      } else {
        const u32* pa = &arrive1[(((t - 1) & (FSLOT - 1)) * 8 + cl) * 16];
        const u32* pb = &arrive0[((t & (FSLOT - 1)) * 8 + cl) * 16];
        if (t > 0) spin16x2(pa, t, pb, t + 1);
        else       spin16(pb, 1);
      }
    }
    __syncthreads();

    // ---- stage into swizzled LDS [b][k]
    if (LAYER == 0) {
      { // x from regs: row slR(=b), bytes bR*16
        const int off = (bR * 16) ^ ((slR & 7) << 4);
        *(i32x4*)(inbH + slR * RB + off) = xH;
        *(i32x4*)(inbL + slR * RB + off) = xL;
      }
      { // h0[t-1]: k bytes 256 + slR*32
        const size_t e = relem((t - 1) & (RING - 1), cl, slR, bR);
        i32x4 H0, H1, L0v, L1v;
        ld_coh_p2(r0h + e, r0l + e, H0, H1, L0v, L1v);
        const int o0 = (256 + slR * 32) ^ xorB, o1 = (256 + slR * 32 + 16) ^ xorB;
        *(i32x4*)(inbH + bR * RB + o0) = H0;
        *(i32x4*)(inbH + bR * RB + o1) = H1;
        *(i32x4*)(inbL + bR * RB + o0) = L0v;
        *(i32x4*)(inbL + bR * RB + o1) = L1v;
      }
    } else {
      // h0[t] -> k bytes slR*32 ; h1[t-1] -> k bytes 512 + slR*32 (one RT)
      const size_t e0 = relem(t & (RING - 1), cl, slR, bR);
      const size_t e1 = relem((t - 1) & (RING - 1), cl, slR, bR);
      i32x4 A0, A1, B0, B1, C0, C1, D0, D1;
      ld_coh_p4(r0h + e0, r0l + e0, r1h + e1, r1l + e1,
                A0, A1, B0, B1, C0, C1, D0, D1);
      const int oa0 = (slR * 32) ^ xorB,       oa1 = (slR * 32 + 16) ^ xorB;
      const int ob0 = (512 + slR * 32) ^ xorB, ob1 = (512 + slR * 32 + 16) ^ xorB;
      *(i32x4*)(inbH + bR * RB + oa0) = A0;
      *(i32x4*)(inbH + bR * RB + oa1) = A1;
      *(i32x4*)(inbL + bR * RB + oa0) = B0;
      *(i32x4*)(inbL + bR * RB + oa1) = B1;
      *(i32x4*)(inbH + bR * RB + ob0) = C0;
      *(i32x4*)(inbH + bR * RB + ob1) = C1;
      *(i32x4*)(inbL + bR * RB + ob0) = D0;
      *(i32x4*)(inbL + bR * RB + ob1) = D1;
    }
    __syncthreads();

    // ---- MFMA: 2 interleaved K-half accumulators
    f32x4 accA = {0.f, 0.f, 0.f, 0.f};
    f32x4 accB = {0.f, 0.f, 0.f, 0.f};
    const char* bbH = inbH + r15 * RB;
    const char* bbL = inbL + r15 * RB;
    const int bxor = (r15 & 7) << 4;
#pragma unroll
    for (int i = 0; i < NH; ++i) {
      const int offA = (i * 64 + kg * 16) ^ bxor;
      const int offB = ((i + NH) * 64 + kg * 16) ^ bxor;
      s16x8 bHA = __builtin_bit_cast(s16x8, *(const i32x4*)(bbH + offA));
      s16x8 bLA = __builtin_bit_cast(s16x8, *(const i32x4*)(bbL + offA));
      s16x8 bHB = __builtin_bit_cast(s16x8, *(const i32x4*)(bbH + offB));
      s16x8 bLB = __builtin_bit_cast(s16x8, *(const i32x4*)(bbL + offB));
      accA = __builtin_amdgcn_mfma_f32_16x16x32_bf16(wAh[i],      bHA, accA, 0, 0, 0);
      accB = __builtin_amdgcn_mfma_f32_16x16x32_bf16(wAh[i + NH], bHB, accB, 0, 0, 0);
      accA = __builtin_amdgcn_mfma_f32_16x16x32_bf16(wAh[i],      bLA, accA, 0, 0, 0);
      accB = __builtin_amdgcn_mfma_f32_16x16x32_bf16(wAh[i + NH], bLB, accB, 0, 0, 0);
      accA = __builtin_amdgcn_mfma_f32_16x16x32_bf16(wAl[i],      bHA, accA, 0, 0, 0);
      accB = __builtin_amdgcn_mfma_f32_16x16x32_bf16(wAl[i + NH], bHB, accB, 0, 0, 0);
    }
#pragma unroll
    for (int r = 0; r < 4; ++r)
      gatesS[(wv * 16 + kg * 4 + r) * 17 + r15] = accA[r] + accB[r];
    __syncthreads();

    // ---- elementwise: thread = (u = tid&15, b = tid>>4), one unit
    {
      const int u = tid & 15, b = tid >> 4;
      float pi = gatesS[(0 * 16 + u) * 17 + b] + biasS[u];
      float pf = gatesS[(1 * 16 + u) * 17 + b] + biasS[16 + u];
      float pg = gatesS[(2 * 16 + u) * 17 + b] + biasS[32 + u];
      float po = gatesS[(3 * 16 + u) * 17 + b] + biasS[48 + u];
      float c = cpr * sigm(pf) + sigm(pi) * tanhf(pg);
      cpr = c;
      float hv = sigm(po) * tanhf(c);
      u16 hh, ll;
      split_bf(hv, hh, ll);
      u32 me = (u32)hh | ((u32)ll << 16);
      u32 nb = (u32)__shfl_down((int)me, 1);
      if ((u & 1) == 0) {
        u32 hiw = (me & 0xFFFFu) | ((nb & 0xFFFFu) << 16);
        u32 low = (me >> 16) | (nb & 0xFFFF0000u);
        const size_t eb = relem(t & (RING - 1), cl, sl, b) + u;
        st_coh_u32((LAYER ? r1h : r0h) + eb, hiw);
        st_coh_u32((LAYER ? r1l : r0l) + eb, low);
      }
    }
    asm volatile("s_waitcnt vmcnt(0)" ::: "memory");
    __syncthreads();
    if (tid == 0) {
      u32* arr = LAYER ? arrive1 : arrive0;
      st_coh_u32(&arr[((t & (FSLOT - 1)) * 8 + cl) * 16 + sl], (u32)(t + 1));
    }
  }

  // ---- final FC (fp32 from hi+lo): one wg per cluster
  if (LAYER == 1 && sl == 0) {
    if (tid == 0)
      spin16(&arrive1[((1023 & (FSLOT - 1)) * 8 + cl) * 16], 1024);
    __syncthreads();
    {  // stage h1[1023] (slR,bR row: 32B hi + 32B lo) into LDS linear
      const size_t e = relem(1023 & (RING - 1), cl, slR, bR);
      i32x4 H0, H1, L0v, L1v;
      ld_coh_p2(r1h + e, r1l + e, H0, H1, L0v, L1v);
      *(i32x4*)(inbH + (slR * 16 + bR) * 32)      = H0;
      *(i32x4*)(inbH + (slR * 16 + bR) * 32 + 16) = H1;
      *(i32x4*)(inbL + (slR * 16 + bR) * 32)      = L0v;
      *(i32x4*)(inbL + (slR * 16 + bR) * 32 + 16) = L1v;
    }
    __syncthreads();
    if (tid < 160) {
      const int b = tid / 10, oo = tid % 10;
      const u16* fH = (const u16*)inbH;
      const u16* fL = (const u16*)inbL;
      float sum = bfc[oo];
      for (int u = 0; u < 256; ++u) {
        const int elem = (((u >> 4) * 16 + b) * 16) + (u & 15);
        float v = bf2f(fH[elem]) + bf2f(fL[elem]);
        sum += v * Wfc[oo * 256 + u];
      }
      out[(cl * 16 + b) * 10 + oo] = sum;
    }
  }
}

__launch_bounds__(256, 2)
__global__ void lstm_kernel(const float* __restrict__ x,
    const float* __restrict__ Wxh0, const float* __restrict__ bxh0,
    const float* __restrict__ Whh0, const float* __restrict__ bhh0,
    const float* __restrict__ Wxh1, const float* __restrict__ bxh1,
    const float* __restrict__ Whh1, const float* __restrict__ bhh1,
    const float* __restrict__ Wfc, const float* __restrict__ bfc,
    float* __restrict__ out, char* __restrict__ ws)
{
  __shared__ __align__(16) char inbH[16 * 1024];
  __shared__ __align__(16) char inbL[16 * 1024];
  __shared__ float gatesS[64 * 17];
  __shared__ float biasS[64];

  // ws: 4 bf16 planes [8][8cl][16sl][16b][16u] (512KB each); flags at 2MB
  u16* r0h = (u16*)ws;
  u16* r0l = (u16*)(ws + (512u << 10));
  u16* r1h = (u16*)(ws + (1024u << 10));
  u16* r1l = (u16*)(ws + (1536u << 10));
  u32* arrive0 = (u32*)(ws + (2048u << 10));   // [16 slots][8 cl][16 sl] u32
  u32* arrive1 = arrive0 + FSLOT * 8 * 16;

  const int bid = blockIdx.x;
  const int cl    = bid & 7;
  const int layer = (bid >> 3) & 1;
  const int sl    = bid >> 4;        // 0..15

  if (layer == 0)
    run_layer<0>(cl, sl, x, Wxh0, bxh0, Whh0, bhh0, Wfc, bfc, out,
                 r0h, r0l, r1h, r1l, arrive0, arrive1, inbH, inbL, gatesS, biasS);
  else
    run_layer<1>(cl, sl, x, Wxh1, bxh1, Whh1, bhh1, Wfc, bfc, out,
                 r0h, r0l, r1h, r1l, arrive0, arrive1, inbH, inbL, gatesS, biasS);
}

extern "C" void kernel_launch(void* const* d_in, const int* in_sizes, int n_in,
                              void* d_out, int out_size, void* d_ws, size_t ws_size,
                              hipStream_t stream) {
  const float* x    = (const float*)d_in[0];
  const float* Wxh0 = (const float*)d_in[1];
  const float* bxh0 = (const float*)d_in[2];
  const float* Whh0 = (const float*)d_in[3];
  const float* bhh0 = (const float*)d_in[4];
  const float* Wxh1 = (const float*)d_in[5];
  const float* bxh1 = (const float*)d_in[6];
  const float* Whh1 = (const float*)d_in[7];
  const float* bhh1 = (const float*)d_in[8];
  const float* Wfc  = (const float*)d_in[9];
  const float* bfc  = (const float*)d_in[10];
  float* out = (float*)d_out;
  char* ws = (char*)d_ws;

  // zero rings (slot 7 read as h[-1]=0 at t=0) + token flags
  size_t zero_bytes = (size_t)(2048u << 10) + (size_t)2 * FSLOT * 8 * 16 * sizeof(u32);
  hipMemsetAsync(d_ws, 0, zero_bytes, stream);

  lstm_kernel<<<dim3(256), dim3(256), 0, stream>>>(
      x, Wxh0, bxh0, Whh0, bhh0, Wxh1, bxh1, Whh1, bhh1, Wfc, bfc, out, ws);
}